// Round 1
// baseline (16.663 us; speedup 1.0000x reference)
//
#include <hip/hip_runtime.h>

#define KW 5
#define LL 8192
#define PP 8188   // L - K + 1

__global__ __launch_bounds__(256) void qconv_kernel(
    const float* __restrict__ x, const float* __restrict__ w, float* __restrict__ out)
{
    int p = blockIdx.x * 256 + threadIdx.x;
    int b = blockIdx.y;
    if (p >= PP) return;

    // weights -> rotation scalars (cheap, per-thread; w is L2/scalar-cached)
    float phi = w[0], theta = w[1];
    float st, ct, sp, cp;
    sincosf(theta, &st, &ct);
    sincosf(phi, &sp, &cp);

    const float* xp = x + b * LL + p;

    // Per-wire qubit amplitudes:
    //   a = 0.5*atan(x), bb = 0.5*atan(x^2)
    //   q0 = cos(a)*e^{-i bb},  q1 = sin(a)*e^{+i bb}
    // Half-angle closed forms (c = cos(atan(u)) = rsqrt(1+u^2)):
    //   cos(a) = sqrt(0.5*(1+c)),  sin(a) = u*c*sqrt(0.5/(1+c))  (cancellation-free)
    float q0r[KW], q0i[KW], q1r[KW], q1i[KW];
#pragma unroll
    for (int wv = 0; wv < KW; ++wv) {
        float xv = xp[wv];
        float x2 = xv * xv;
        float x4 = x2 * x2;
        float c1 = rsqrtf(1.0f + x2);   // cos(atan(x))
        float c2 = rsqrtf(1.0f + x4);   // cos(atan(x^2))
        float ca = sqrtf(0.5f * (1.0f + c1));
        float sa = xv * c1 * (0.70710678118f * rsqrtf(1.0f + c1));
        float cb = sqrtf(0.5f * (1.0f + c2));
        float sb = x2 * c2 * (0.70710678118f * rsqrtf(1.0f + c2));
        q0r[wv] = ca * cb;  q0i[wv] = -ca * sb;
        q1r[wv] = sa * cb;  q1i[wv] = sa * sb;
    }

    // Tensor product: state[m] = q_0[m4]*q_1[m3]*q_2[m2]*q_3[m1]*q_4[m0]
    // (wire 0 = MSB). Built in-place, fully unrolled -> registers.
    float sr[32], si[32];
    sr[0] = q0r[0]; si[0] = q0i[0];
    sr[1] = q1r[0]; si[1] = q1i[0];

#define EXPAND(WV, CUR)                                  \
    _Pragma("unroll")                                    \
    for (int i = (CUR) - 1; i >= 0; --i) {               \
        float ar = sr[i], ai = si[i];                    \
        sr[2*i+1] = ar * q1r[WV] - ai * q1i[WV];         \
        si[2*i+1] = ar * q1i[WV] + ai * q1r[WV];         \
        sr[2*i]   = ar * q0r[WV] - ai * q0i[WV];         \
        si[2*i]   = ar * q0i[WV] + ai * q0r[WV];         \
    }
    EXPAND(1, 2)
    EXPAND(2, 4)
    EXPAND(3, 8)
    EXPAND(4, 16)
#undef EXPAND

    // Ring-CNOT perm in closed form:
    //   perm bits: m4=b4^b0, m3=b3^b4^b0, m2=b2^b3, m1=b1^b2, m0=b0^b1
    //   => b4 (the U-row split) = parity(m & 15); pair partner = m ^ 24.
    // z = cos(th)*S1 - 2 sin(th)*(cos(phi)*Re(S2) + sin(phi)*Im(S2))
    float S1 = 0.f, S2r = 0.f, S2i = 0.f;
#pragma unroll
    for (int m = 0; m < 32; ++m) {
        if (__builtin_popcount(m & 15) & 1) continue;   // v0 slots only
        const int mm = m ^ 24;                          // matching v1 slot
        float v0r = sr[m],  v0i = si[m];
        float v1r = sr[mm], v1i = si[mm];
        S1  += (v0r*v0r + v0i*v0i) - (v1r*v1r + v1i*v1i);
        S2r += v0r*v1r + v0i*v1i;   // Re(v0*conj(v1))
        S2i += v0i*v1r - v0r*v1i;   // Im(v0*conj(v1))
    }

    out[b * PP + p] = ct * S1 - 2.0f * st * (cp * S2r + sp * S2i);
}

extern "C" void kernel_launch(void* const* d_in, const int* in_sizes, int n_in,
                              void* d_out, int out_size, void* d_ws, size_t ws_size,
                              hipStream_t stream) {
    const float* x = (const float*)d_in[0];
    const float* w = (const float*)d_in[1];
    float* out = (float*)d_out;
    dim3 grid((PP + 255) / 256, 64);  // 32 x 64 blocks, 256 threads
    qconv_kernel<<<grid, dim3(256), 0, stream>>>(x, w, out);
}

// Round 2
// 10.001 us; speedup vs baseline: 1.6662x; 1.6662x over previous
//
#include <hip/hip_runtime.h>

#define LL 8192
#define PP 8188   // L - K + 1

// Closed form of the 5-qubit windowed circuit:
//   c_i = rsqrt(1+x_i^2) = cos(atan x_i)
//   d_i = rsqrt(1+x_i^4) = cos(atan x_i^2)
//   e_i = x_i * c_i * d_i
//   C   = c_{p+2} * c_{p+3} * c_{p+4}
//   z_p = cos(th)*c_{p+1}*C - sin(th)*e_p*e_{p+1}*(cos(phi) - sin(phi)*x_{p+1}^2*C)
// (omega cancels exactly.)
__global__ __launch_bounds__(256) void qconv_kernel(
    const float* __restrict__ x, const float* __restrict__ w, float* __restrict__ out)
{
    int t = blockIdx.x * 256 + threadIdx.x;   // 131072 threads
    int b = t >> 11;                          // row (64)
    int chunk = t & 2047;                     // 2048 chunks/row
    int p0 = chunk << 2;                      // 4 outputs per thread
    if (p0 >= PP) return;                     // chunk 2047 fully invalid

    float phi = w[0], theta = w[1];
    float st, ct, sp, cp;
    sincosf(theta, &st, &ct);
    sincosf(phi, &sp, &cp);

    const float* xp = x + b * LL + p0;
    float4 u0 = *(const float4*)(xp);
    float4 u1 = *(const float4*)(xp + 4);
    float xv[8] = {u0.x, u0.y, u0.z, u0.w, u1.x, u1.y, u1.z, u1.w};

    float c[8], e[8], f[8];
#pragma unroll
    for (int i = 0; i < 8; ++i) {
        float xx = xv[i];
        float x2 = xx * xx;
        float ci = rsqrtf(1.0f + x2);
        float di = rsqrtf(1.0f + x2 * x2);
        c[i] = ci;
        e[i] = xx * ci * di;
        f[i] = x2;
    }

    float4 z;
    float* zp = &z.x;
#pragma unroll
    for (int k = 0; k < 4; ++k) {
        float C = c[k + 2] * c[k + 3] * c[k + 4];
        zp[k] = ct * c[k + 1] * C
              - st * e[k] * e[k + 1] * (cp - sp * f[k + 1] * C);
    }

    *(float4*)(out + b * PP + p0) = z;
}

extern "C" void kernel_launch(void* const* d_in, const int* in_sizes, int n_in,
                              void* d_out, int out_size, void* d_ws, size_t ws_size,
                              hipStream_t stream) {
    const float* x = (const float*)d_in[0];
    const float* w = (const float*)d_in[1];
    float* out = (float*)d_out;
    qconv_kernel<<<dim3(512), dim3(256), 0, stream>>>(x, w, out);
}